// Round 8
// baseline (464.603 us; speedup 1.0000x reference)
//
#include <hip/hip_runtime.h>

#define NVOX 262144     // 64^3
#define NB   256        // buckets = top 8 bits of lin
#define VPB  1024       // voxels per bucket = low 10 bits
#define PPB  4096       // points per block in binning passes
#define SCT  512        // scatter threads
#define NBLK 256        // fallback voxel-walker blocks

// ======================= shared: padding fill ===============================
__global__ void dv_fill(const unsigned* __restrict__ nuP,
                        float* __restrict__ out, int n) {
    int nu = (int)*nuP;
    size_t meanChunks = (size_t)n * 7 / 4;
    size_t coordChunks = (size_t)n * 3 / 4;
    size_t total = meanChunks + coordChunks;
    size_t i = (size_t)blockIdx.x * blockDim.x + threadIdx.x;
    if (i >= total) return;
    float* mean = out;
    float* coords = out + (size_t)n * 7;
    if (i < meanChunks) {
        size_t base = i * 4, lim = (size_t)nu * 7;
        if (base >= lim) {
            *(float4*)(mean + base) = make_float4(0.f, 0.f, 0.f, 0.f);
        } else if (base + 4 > lim) {
            for (size_t k = lim; k < base + 4; ++k) mean[k] = 0.f;
        }
    } else {
        size_t base = (i - meanChunks) * 4, lim = (size_t)nu * 3;
        if (base >= lim) {
            *(float4*)(coords + base) = make_float4(-1.f, -1.f, -1.f, -1.f);
        } else if (base + 4 > lim) {
            for (size_t k = lim; k < base + 4; ++k) coords[k] = -1.f;
        }
    }
}

// ======================= RADIX (fat-record) PATH ============================
// P1: per-block LDS histogram over 256 buckets (coalesced global write)
__global__ void rx_hist(const int* __restrict__ gi, int n,
                        unsigned* __restrict__ blockHist) {
    __shared__ unsigned h[NB];
    int t = threadIdx.x, b = blockIdx.x;
    h[t] = 0;
    __syncthreads();
    int base = b * PPB;
#pragma unroll
    for (int k = 0; k < PPB / 256; ++k) {
        int i = base + k * 256 + t;
        if (i < n) {
            int g0 = gi[3 * i], g1 = gi[3 * i + 1];
            atomicAdd(&h[(g0 << 2) | (g1 >> 4)], 1u);
        }
    }
    __syncthreads();
    blockHist[(size_t)b * NB + t] = h[t];
}

// P2a: per-bucket totals (one block per bucket)
__global__ void rx_bucketsum(const unsigned* __restrict__ blockHist, int nb1,
                             unsigned* __restrict__ bucketCount) {
    int bk = blockIdx.x, t = threadIdx.x;
    unsigned s = 0;
    for (int blk = t; blk < nb1; blk += 256) s += blockHist[(size_t)blk * NB + bk];
    __shared__ unsigned sm[256];
    sm[t] = s;
    __syncthreads();
    for (int off = 128; off > 0; off >>= 1) {
        if (t < off) sm[t] += sm[t + off];
        __syncthreads();
    }
    if (t == 0) bucketCount[bk] = sm[0];
}

// P2b / P5: exclusive scan of 256 values; out[256] = total
__global__ void rx_scan256(const unsigned* __restrict__ in,
                           unsigned* __restrict__ out) {
    __shared__ unsigned sm[NB];
    int t = threadIdx.x;
    unsigned mine = in[t];
    sm[t] = mine;
    __syncthreads();
    for (int off = 1; off < NB; off <<= 1) {
        unsigned v = (t >= off) ? sm[t - off] : 0u;
        __syncthreads();
        sm[t] += v;
        __syncthreads();
    }
    out[t] = sm[t] - mine;
    if (t == NB - 1) out[NB] = sm[t];
}

// P2c: per-bucket exclusive scan over block hists (in place, + bucketBase)
__global__ void rx_blockscan(unsigned* __restrict__ blockHist, int nb1,
                             const unsigned* __restrict__ bucketBase) {
    int bk = blockIdx.x, t = threadIdx.x;
    __shared__ unsigned sm[256];
    __shared__ unsigned carry;
    if (t == 0) carry = bucketBase[bk];
    __syncthreads();
    for (int chunk = 0; chunk * 256 < nb1; ++chunk) {
        int blk = chunk * 256 + t;
        unsigned v = (blk < nb1) ? blockHist[(size_t)blk * NB + bk] : 0u;
        sm[t] = v;
        __syncthreads();
        for (int off = 1; off < 256; off <<= 1) {
            unsigned u = (t >= off) ? sm[t - off] : 0u;
            __syncthreads();
            sm[t] += u;
            __syncthreads();
        }
        if (blk < nb1) blockHist[(size_t)blk * NB + bk] = carry + sm[t] - v;
        __syncthreads();
        if (t == 255) carry += sm[255];
        __syncthreads();
    }
}

// P3: block counting-sort scatter, PPB=4096 -> avg 512B runs. Points are
// gathered directly from global (block's 112KB window is L1/L2-hot).
__global__ void __launch_bounds__(SCT) rx_scatter(
        const int* __restrict__ gi, const float* __restrict__ pts, int n,
        const unsigned* __restrict__ blockHist, float* __restrict__ recs) {
    __shared__ unsigned hist[NB];
    __shared__ unsigned bucketStart[NB];
    __shared__ unsigned runStartS[NB];
    __shared__ unsigned short sortedLid[PPB];   // 8 KB
    __shared__ unsigned dstp[PPB];              // 16 KB: (globalDst<<10)|sub
    int t = threadIdx.x, b = blockIdx.x;
    int base = b * PPB;
    int cnt = n - base;
    if (cnt > PPB) cnt = PPB;
    if (t < NB) { hist[t] = 0; runStartS[t] = blockHist[(size_t)b * NB + t]; }
    __syncthreads();
    unsigned pk[PPB / SCT];    // (bk<<10)|sub
    unsigned posA[PPB / SCT];
#pragma unroll
    for (int k = 0; k < PPB / SCT; ++k) {
        int lid = k * SCT + t;
        if (lid < cnt) {
            int i = base + lid;
            int g0 = gi[3 * i], g1 = gi[3 * i + 1], g2 = gi[3 * i + 2];
            int bk = (g0 << 2) | (g1 >> 4);
            int sub = ((g1 & 15) << 6) | g2;
            pk[k] = ((unsigned)bk << 10) | (unsigned)sub;
            posA[k] = atomicAdd(&hist[bk], 1u);
        }
    }
    __syncthreads();
    // exclusive scan of hist (first 256 threads carry the work)
    unsigned mine = (t < NB) ? hist[t] : 0u;
    for (int d = 1; d < NB; d <<= 1) {
        unsigned v = (t < NB && t >= d) ? hist[t - d] : 0u;
        __syncthreads();
        if (t < NB) hist[t] += v;
        __syncthreads();
    }
    if (t < NB) bucketStart[t] = hist[t] - mine;
    __syncthreads();
#pragma unroll
    for (int k = 0; k < PPB / SCT; ++k) {
        int lid = k * SCT + t;
        if (lid < cnt) {
            unsigned bk = pk[k] >> 10, sub = pk[k] & 1023u;
            unsigned sp = bucketStart[bk] + posA[k];
            unsigned d = runStartS[bk] + posA[k];
            sortedLid[sp] = (unsigned short)lid;
            dstp[sp] = (d << 10) | sub;
        }
    }
    __syncthreads();
    // emit: lane j -> sorted record j; consecutive lanes -> consecutive
    // global slots within each ~512B run -> coalesced bursts
#pragma unroll
    for (int k = 0; k < PPB / SCT; ++k) {
        int j = k * SCT + t;
        if (j < cnt) {
            int lid = sortedLid[j];
            unsigned u = dstp[j];
            unsigned d = u >> 10, sub = u & 1023u;
            const float* r = pts + (size_t)(base + lid) * 7;
            float f0 = r[0], f1 = r[1], f2 = r[2], f3 = r[3];
            float f4 = r[4], f5 = r[5], f6 = r[6];
            float4* o = (float4*)(recs + (size_t)d * 8);
            o[0] = make_float4(f0, f1, f2, f3);
            o[1] = make_float4(f4, f5, f6, __uint_as_float(sub));
        }
    }
}

// P4: per-bucket accumulation via physical counting-sort into LDS.
// Per 1024-record chunk: coalesced load to regs, LDS hist (1 atomic),
// 2-barrier hierarchical scan, rank (1 atomic) + ds_write_b128 into sorted
// LDS slots, then each thread reads its voxel's segment contiguously.
__global__ void __launch_bounds__(1024) rx_accum(
        const float* __restrict__ recs,
        const unsigned* __restrict__ bucketBase,
        float* __restrict__ accTable, unsigned* __restrict__ occCount) {
    __shared__ __align__(16) float sortedR[1024 * 8];   // 32 KB
    __shared__ unsigned off[VPB];                       // 4 KB
    __shared__ unsigned wsum[16];
    int t = threadIdx.x, bk = blockIdx.x;
    int lane = t & 63, wid = t >> 6;
    unsigned s = bucketBase[bk], e = bucketBase[bk + 1];
    float a0 = 0.f, a1 = 0.f, a2 = 0.f, a3 = 0.f,
          a4 = 0.f, a5 = 0.f, a6 = 0.f, cf = 0.f;
    for (unsigned cs = s; cs < e; cs += 1024) {
        bool valid = (cs + t) < e;
        float4 r0, r1;
        unsigned key = 0;
        if (valid) {
            const float4* r = (const float4*)(recs + (size_t)(cs + t) * 8);
            r0 = r[0];
            r1 = r[1];
            key = __float_as_uint(r1.w);
        }
        off[t] = 0;
        __syncthreads();
        if (valid) atomicAdd(&off[key], 1u);
        __syncthreads();
        unsigned own = off[t];
        // hierarchical inclusive scan: wave shfl scan + 16 wave-sums
        unsigned x = own;
#pragma unroll
        for (int d = 1; d < 64; d <<= 1) {
            unsigned y = __shfl_up(x, d, 64);
            if (lane >= d) x += y;
        }
        if (lane == 63) wsum[wid] = x;
        __syncthreads();
        if (t < 64) {
            unsigned w = (lane < 16) ? wsum[lane] : 0u;
            unsigned xx = w;
#pragma unroll
            for (int d = 1; d < 16; d <<= 1) {
                unsigned y = __shfl_up(xx, d, 64);
                if (lane >= d) xx += y;
            }
            if (lane < 16) wsum[lane] = xx - w;   // exclusive wave prefix
        }
        __syncthreads();
        unsigned excl = x - own + wsum[wid];
        off[t] = excl;
        __syncthreads();
        if (valid) {
            unsigned pos = atomicAdd(&off[key], 1u);
            float4* d = (float4*)&sortedR[pos * 8];
            d[0] = r0;
            d[1] = r1;
        }
        __syncthreads();
        // off[v] is now end_v; start_v = off[v-1]
        unsigned end = off[t], st = t ? off[t - 1] : 0u;
        for (unsigned k = st; k < end; ++k) {
            float4 lo = *(const float4*)&sortedR[k * 8];
            float4 hi = *(const float4*)&sortedR[k * 8 + 4];
            a0 += lo.x; a1 += lo.y; a2 += lo.z; a3 += lo.w;
            a4 += hi.x; a5 += hi.y; a6 += hi.z; cf += 1.f;
        }
        __syncthreads();   // before off/sortedR reuse next chunk
    }
    float4* o = (float4*)(accTable + ((size_t)bk * VPB + t) * 8);
    o[0] = make_float4(a0, a1, a2, a3);
    o[1] = make_float4(a4, a5, a6, cf);
    unsigned long long m = __ballot(cf > 0.f);
    if (lane == 0) wsum[wid] = (unsigned)__popcll(m);
    __syncthreads();
    if (t == 0) {
        unsigned occ = 0;
#pragma unroll
        for (int w = 0; w < 16; ++w) occ += wsum[w];
        occCount[bk] = occ;
    }
}

// P6: emit compacted means + coords from accTable
__global__ void rx_emit(const float* __restrict__ accTable,
                        const unsigned* __restrict__ rankBase,
                        float* __restrict__ out_mean,
                        float* __restrict__ out_coords) {
    int bk = blockIdx.x, t = threadIdx.x;
    float row[4][8];
    int pre[4], mycount = 0;
#pragma unroll
    for (int j = 0; j < 4; ++j) {
        int v = t * 4 + j;
        const float4* a = (const float4*)(accTable + ((size_t)bk * VPB + v) * 8);
        float4 r0 = a[0], r1 = a[1];
        row[j][0] = r0.x; row[j][1] = r0.y; row[j][2] = r0.z; row[j][3] = r0.w;
        row[j][4] = r1.x; row[j][5] = r1.y; row[j][6] = r1.z; row[j][7] = r1.w;
        pre[j] = mycount;
        mycount += (row[j][7] > 0.f) ? 1 : 0;
    }
    __shared__ int sm[256];
    sm[t] = mycount;
    __syncthreads();
    for (int off = 1; off < 256; off <<= 1) {
        int v = (t >= off) ? sm[t - off] : 0;
        __syncthreads();
        sm[t] += v;
        __syncthreads();
    }
    int rank0 = (int)rankBase[bk] + (sm[t] - mycount);
#pragma unroll
    for (int j = 0; j < 4; ++j) {
        if (row[j][7] > 0.f) {
            int r = rank0 + pre[j];
            int lin = (bk << 10) | (t * 4 + j);
            float inv = 1.0f / row[j][7];
            float* m = out_mean + (size_t)r * 7;
#pragma unroll
            for (int k = 0; k < 7; ++k) m[k] = row[j][k] * inv;
            float* cd = out_coords + (size_t)r * 3;
            cd[0] = (float)(lin >> 12);
            cd[1] = (float)((lin >> 6) & 63);
            cd[2] = (float)(lin & 63);
        }
    }
}

// ======================= FALLBACK PATH (round-3, proven) ====================
struct Meta {
    unsigned blockSums[NBLK];
    unsigned blockFlagSums[NBLK];
    unsigned blockOffs[NBLK];
    unsigned blockRankOffs[NBLK];
    unsigned nUnique;
};

__global__ void dv_count(const int* __restrict__ gi, int n,
                         unsigned* __restrict__ counts,
                         unsigned short* __restrict__ slots) {
    int i = blockIdx.x * blockDim.x + threadIdx.x;
    if (i >= n) return;
    int lin = (gi[3 * i] << 12) | (gi[3 * i + 1] << 6) | gi[3 * i + 2];
    unsigned s = atomicAdd(&counts[lin], 1u);
    slots[i] = (unsigned short)s;
}

__global__ void dv_bs1(const unsigned* __restrict__ counts,
                       Meta* __restrict__ meta) {
    int b = blockIdx.x, t = threadIdx.x;
    uint4 c = ((const uint4*)(counts + (size_t)b * 1024))[t];
    unsigned cs = c.x + c.y + c.z + c.w;
    unsigned fs = (c.x > 0) + (c.y > 0) + (c.z > 0) + (c.w > 0);
    __shared__ unsigned smC[256], smF[256];
    smC[t] = cs; smF[t] = fs;
    __syncthreads();
    for (int off = 128; off > 0; off >>= 1) {
        if (t < off) { smC[t] += smC[t + off]; smF[t] += smF[t + off]; }
        __syncthreads();
    }
    if (t == 0) { meta->blockSums[b] = smC[0]; meta->blockFlagSums[b] = smF[0]; }
}

__global__ void dv_scan2(unsigned* __restrict__ offsets, int n,
                         Meta* __restrict__ meta) {
    __shared__ unsigned smC[NBLK], smF[NBLK];
    int t = threadIdx.x;
    unsigned c = meta->blockSums[t], f = meta->blockFlagSums[t];
    smC[t] = c; smF[t] = f;
    __syncthreads();
    for (int off = 1; off < NBLK; off <<= 1) {
        unsigned vc = (t >= off) ? smC[t - off] : 0u;
        unsigned vf = (t >= off) ? smF[t - off] : 0u;
        __syncthreads();
        smC[t] += vc; smF[t] += vf;
        __syncthreads();
    }
    meta->blockOffs[t] = smC[t] - c;
    meta->blockRankOffs[t] = smF[t] - f;
    if (t == NBLK - 1) { meta->nUnique = smF[t]; offsets[NVOX] = (unsigned)n; }
}

__global__ void dv_scan3(unsigned* __restrict__ counts,
                         const Meta* __restrict__ meta) {
    int b = blockIdx.x, t = threadIdx.x;
    uint4 c = ((const uint4*)(counts + (size_t)b * 1024))[t];
    unsigned mysum = c.x + c.y + c.z + c.w;
    __shared__ unsigned sm[256];
    sm[t] = mysum;
    __syncthreads();
    for (int off = 1; off < 256; off <<= 1) {
        unsigned v = (t >= off) ? sm[t - off] : 0u;
        __syncthreads();
        sm[t] += v;
        __syncthreads();
    }
    unsigned base = meta->blockOffs[b] + sm[t] - mysum;
    uint4 o;
    o.x = base;
    o.y = base + c.x;
    o.z = o.y + c.y;
    o.w = o.z + c.z;
    ((uint4*)(counts + (size_t)b * 1024))[t] = o;
}

__global__ void dv_scatter2(const int* __restrict__ gi, int n,
                            const unsigned* __restrict__ offsets,
                            const unsigned short* __restrict__ slots,
                            unsigned* __restrict__ perm) {
    int i = blockIdx.x * blockDim.x + threadIdx.x;
    if (i >= n) return;
    int lin = (gi[3 * i] << 12) | (gi[3 * i + 1] << 6) | gi[3 * i + 2];
    perm[offsets[lin] + (unsigned)slots[i]] = (unsigned)i;
}

__global__ void dv_emit2(const float* __restrict__ points,
                         const unsigned* __restrict__ offsets,
                         const unsigned* __restrict__ perm,
                         const Meta* __restrict__ meta,
                         float* __restrict__ out_mean,
                         float* __restrict__ out_coords) {
    int b = blockIdx.x, t = threadIdx.x;
    int base = b * 1024 + t * 4;
    uint4 o4 = ((const uint4*)offsets)[b * 256 + t];
    unsigned o[5];
    o[0] = o4.x; o[1] = o4.y; o[2] = o4.z; o[3] = o4.w;
    o[4] = offsets[base + 4];
    int c[4], pre[4], mycount = 0;
#pragma unroll
    for (int j = 0; j < 4; ++j) {
        c[j] = (int)(o[j + 1] - o[j]);
        pre[j] = mycount;
        mycount += (c[j] > 0) ? 1 : 0;
    }
    __shared__ int sm[256];
    sm[t] = mycount;
    __syncthreads();
    for (int off = 1; off < 256; off <<= 1) {
        int v = (t >= off) ? sm[t - off] : 0;
        __syncthreads();
        sm[t] += v;
        __syncthreads();
    }
    int rank0 = (int)meta->blockRankOffs[b] + (sm[t] - mycount);
#pragma unroll
    for (int j = 0; j < 4; ++j) {
        if (c[j] > 0) {
            float s0 = 0.f, s1 = 0.f, s2 = 0.f, s3 = 0.f,
                  s4 = 0.f, s5 = 0.f, s6 = 0.f;
            for (unsigned k = o[j]; k < o[j + 1]; ++k) {
                unsigned idx = perm[k];
                const float* p = points + (size_t)idx * 7;
                s0 += p[0]; s1 += p[1]; s2 += p[2]; s3 += p[3];
                s4 += p[4]; s5 += p[5]; s6 += p[6];
            }
            int r = rank0 + pre[j];
            int v = base + j;
            float inv = 1.0f / (float)c[j];
            float* m = out_mean + (size_t)r * 7;
            m[0] = s0 * inv; m[1] = s1 * inv; m[2] = s2 * inv;
            m[3] = s3 * inv; m[4] = s4 * inv; m[5] = s5 * inv;
            m[6] = s6 * inv;
            float* cd = out_coords + (size_t)r * 3;
            cd[0] = (float)(v >> 12);
            cd[1] = (float)((v >> 6) & 63);
            cd[2] = (float)(v & 63);
        }
    }
}

// ======================= launch =============================================
extern "C" void kernel_launch(void* const* d_in, const int* in_sizes, int n_in,
                              void* d_out, int out_size, void* d_ws, size_t ws_size,
                              hipStream_t stream) {
    const float* points = (const float*)d_in[0];
    const int*   gi     = (const int*)d_in[1];
    int n = in_sizes[0] / 7;   // 4,000,000

    float* out_mean   = (float*)d_out;
    float* out_coords = (float*)d_out + (size_t)n * 7;

    int threads = 256;
    int nb1 = (n + PPB - 1) / PPB;

    size_t recsB = (size_t)n * 8 * sizeof(float);            // 128 MiB
    size_t bhB   = (size_t)nb1 * NB * sizeof(unsigned);      // ~1 MB
    size_t accB  = (size_t)NB * VPB * 8 * sizeof(float);     // 8 MiB
    size_t need  = recsB + bhB + (NB + 1) * 4 + accB + NB * 4 + NB * 4 +
                   (NB + 1) * 4 + 256;

    size_t fillChunks = (size_t)n * 7 / 4 + (size_t)n * 3 / 4;
    int fillBlocks = (int)((fillChunks + threads - 1) / threads);

    if (ws_size >= need) {
        char* w = (char*)d_ws;
        float*    recs        = (float*)w;                 w += recsB;
        unsigned* blockHist   = (unsigned*)w;              w += bhB;
        unsigned* bucketCount = (unsigned*)w;              w += NB * 4;
        unsigned* bucketBase  = (unsigned*)w;              w += (NB + 1) * 4;
        unsigned* occCount    = (unsigned*)w;              w += NB * 4;
        unsigned* rankBase    = (unsigned*)w;              w += (NB + 1) * 4;
        float*    accTable    = (float*)w;

        rx_hist<<<nb1, 256, 0, stream>>>(gi, n, blockHist);
        rx_bucketsum<<<NB, 256, 0, stream>>>(blockHist, nb1, bucketCount);
        rx_scan256<<<1, NB, 0, stream>>>(bucketCount, bucketBase);
        rx_blockscan<<<NB, 256, 0, stream>>>(blockHist, nb1, bucketBase);
        rx_scatter<<<nb1, SCT, 0, stream>>>(gi, points, n, blockHist, recs);
        rx_accum<<<NB, 1024, 0, stream>>>(recs, bucketBase, accTable, occCount);
        rx_scan256<<<1, NB, 0, stream>>>(occCount, rankBase);
        rx_emit<<<NB, 256, 0, stream>>>(accTable, rankBase, out_mean, out_coords);
        dv_fill<<<fillBlocks, threads, 0, stream>>>(rankBase + NB,
                                                    (float*)d_out, n);
    } else {
        char* w = (char*)d_ws;
        unsigned*       perm    = (unsigned*)w;
        unsigned short* slots   = (unsigned short*)(w + (size_t)n * 4);
        unsigned*       offsets = (unsigned*)(w + (size_t)n * 4 + (size_t)n * 2);
        Meta*           meta    = (Meta*)((char*)offsets + (size_t)(NVOX + 4) * 4);

        hipMemsetAsync(offsets, 0, (size_t)(NVOX + 4) * 4, stream);

        int blocksN = (n + threads - 1) / threads;
        dv_count<<<blocksN, threads, 0, stream>>>(gi, n, offsets, slots);
        dv_bs1<<<NBLK, 256, 0, stream>>>(offsets, meta);
        dv_scan2<<<1, NBLK, 0, stream>>>(offsets, n, meta);
        dv_scan3<<<NBLK, 256, 0, stream>>>(offsets, meta);
        dv_scatter2<<<blocksN, threads, 0, stream>>>(gi, n, offsets, slots, perm);
        dv_emit2<<<NBLK, 256, 0, stream>>>(points, offsets, perm, meta,
                                           out_mean, out_coords);
        dv_fill<<<fillBlocks, threads, 0, stream>>>(&meta->nUnique,
                                                    (float*)d_out, n);
    }
}

// Round 9
// 428.016 us; speedup vs baseline: 1.0855x; 1.0855x over previous
//
#include <hip/hip_runtime.h>

#define NVOX 262144     // 64^3
#define NB   256        // buckets = top 8 bits of lin
#define VPB  1024       // voxels per bucket = low 10 bits
#define PPB  2048       // points per block in binning passes
#define SCT  512        // hist/scatter threads
#define NBLK 256        // fallback voxel-walker blocks

// ======================= shared: padding fill ===============================
__global__ void dv_fill(const unsigned* __restrict__ nuP,
                        float* __restrict__ out, int n) {
    int nu = (int)*nuP;
    size_t meanChunks = (size_t)n * 7 / 4;
    size_t coordChunks = (size_t)n * 3 / 4;
    size_t total = meanChunks + coordChunks;
    size_t i = (size_t)blockIdx.x * blockDim.x + threadIdx.x;
    if (i >= total) return;
    float* mean = out;
    float* coords = out + (size_t)n * 7;
    if (i < meanChunks) {
        size_t base = i * 4, lim = (size_t)nu * 7;
        if (base >= lim) {
            *(float4*)(mean + base) = make_float4(0.f, 0.f, 0.f, 0.f);
        } else if (base + 4 > lim) {
            for (size_t k = lim; k < base + 4; ++k) mean[k] = 0.f;
        }
    } else {
        size_t base = (i - meanChunks) * 4, lim = (size_t)nu * 3;
        if (base >= lim) {
            *(float4*)(coords + base) = make_float4(-1.f, -1.f, -1.f, -1.f);
        } else if (base + 4 > lim) {
            for (size_t k = lim; k < base + 4; ++k) coords[k] = -1.f;
        }
    }
}

// ======================= RADIX (fat-record) PATH ============================
// P1: histogram + rank producer. packed[i] = (key<<11) | rank, key=bk<<10|sub.
__global__ void __launch_bounds__(SCT) rx_hist(
        const int* __restrict__ gi, int n,
        unsigned* __restrict__ blockHist, unsigned* __restrict__ packed) {
    __shared__ unsigned h[NB];
    int t = threadIdx.x, b = blockIdx.x;
    if (t < NB) h[t] = 0;
    __syncthreads();
    int base = b * PPB;
    int p0 = base + t * 4;
    if (p0 + 4 <= n) {
        const int4* g4 = (const int4*)(gi + (size_t)base * 3);
        int4 a = g4[3 * t], c = g4[3 * t + 1], d = g4[3 * t + 2];
        unsigned k0 = ((unsigned)((a.x << 2) | (a.y >> 4)) << 10) |
                      (unsigned)(((a.y & 15) << 6) | a.z);
        unsigned k1 = ((unsigned)((a.w << 2) | (c.x >> 4)) << 10) |
                      (unsigned)(((c.x & 15) << 6) | c.y);
        unsigned k2 = ((unsigned)((c.z << 2) | (c.w >> 4)) << 10) |
                      (unsigned)(((c.w & 15) << 6) | d.x);
        unsigned k3 = ((unsigned)((d.y << 2) | (d.z >> 4)) << 10) |
                      (unsigned)(((d.z & 15) << 6) | d.w);
        uint4 o;
        o.x = (k0 << 11) | atomicAdd(&h[k0 >> 10], 1u);
        o.y = (k1 << 11) | atomicAdd(&h[k1 >> 10], 1u);
        o.z = (k2 << 11) | atomicAdd(&h[k2 >> 10], 1u);
        o.w = (k3 << 11) | atomicAdd(&h[k3 >> 10], 1u);
        ((uint4*)(packed + base))[t] = o;
    } else {
        for (int j = 0; j < 4; ++j) {
            int i = p0 + j;
            if (i < n) {
                int g0 = gi[3 * i], g1 = gi[3 * i + 1], g2 = gi[3 * i + 2];
                unsigned key = ((unsigned)((g0 << 2) | (g1 >> 4)) << 10) |
                               (unsigned)(((g1 & 15) << 6) | g2);
                packed[i] = (key << 11) | atomicAdd(&h[key >> 10], 1u);
            }
        }
    }
    __syncthreads();
    if (t < NB) blockHist[(size_t)b * NB + t] = h[t];
}

// P2a: per-bucket totals (one block per bucket)
__global__ void rx_bucketsum(const unsigned* __restrict__ blockHist, int nb1,
                             unsigned* __restrict__ bucketCount) {
    int bk = blockIdx.x, t = threadIdx.x;
    unsigned s = 0;
    for (int blk = t; blk < nb1; blk += 256) s += blockHist[(size_t)blk * NB + bk];
    __shared__ unsigned sm[256];
    sm[t] = s;
    __syncthreads();
    for (int off = 128; off > 0; off >>= 1) {
        if (t < off) sm[t] += sm[t + off];
        __syncthreads();
    }
    if (t == 0) bucketCount[bk] = sm[0];
}

// P2b / P5: exclusive scan of 256 values; out[256] = total
__global__ void rx_scan256(const unsigned* __restrict__ in,
                           unsigned* __restrict__ out) {
    __shared__ unsigned sm[NB];
    int t = threadIdx.x;
    unsigned mine = in[t];
    sm[t] = mine;
    __syncthreads();
    for (int off = 1; off < NB; off <<= 1) {
        unsigned v = (t >= off) ? sm[t - off] : 0u;
        __syncthreads();
        sm[t] += v;
        __syncthreads();
    }
    out[t] = sm[t] - mine;
    if (t == NB - 1) out[NB] = sm[t];
}

// P2c: per-bucket exclusive scan over block hists -> blockOff (run starts)
__global__ void rx_blockscan(const unsigned* __restrict__ blockHist, int nb1,
                             const unsigned* __restrict__ bucketBase,
                             unsigned* __restrict__ blockOff) {
    int bk = blockIdx.x, t = threadIdx.x;
    __shared__ unsigned sm[256];
    __shared__ unsigned carry;
    if (t == 0) carry = bucketBase[bk];
    __syncthreads();
    for (int chunk = 0; chunk * 256 < nb1; ++chunk) {
        int blk = chunk * 256 + t;
        unsigned v = (blk < nb1) ? blockHist[(size_t)blk * NB + bk] : 0u;
        sm[t] = v;
        __syncthreads();
        for (int off = 1; off < 256; off <<= 1) {
            unsigned u = (t >= off) ? sm[t - off] : 0u;
            __syncthreads();
            sm[t] += u;
            __syncthreads();
        }
        if (blk < nb1) blockOff[(size_t)blk * NB + bk] = carry + sm[t] - v;
        __syncthreads();
        if (t == 255) carry += sm[255];
        __syncthreads();
    }
}

// P3: staged counting-sort scatter, zero atomics (ranks precomputed).
__global__ void __launch_bounds__(SCT) rx_scatter(
        const unsigned* __restrict__ packed, const float* __restrict__ pts,
        int n, const unsigned* __restrict__ blockHist,
        const unsigned* __restrict__ blockOff, float* __restrict__ recs) {
    __shared__ __align__(16) float ptsS[PPB * 7];   // 57344 B
    __shared__ unsigned short sortedLid[PPB];       // 4 KB
    __shared__ unsigned dstp[PPB];                  // 8 KB: (dst<<10)|sub
    __shared__ unsigned runS[NB];
    __shared__ unsigned bStart[NB];
    __shared__ unsigned sc[NB];
    int t = threadIdx.x, b = blockIdx.x;
    int base = b * PPB;
    int cnt = n - base;
    if (cnt > PPB) cnt = PPB;
    unsigned mine = 0;
    if (t < NB) {
        runS[t] = blockOff[(size_t)b * NB + t];
        mine = blockHist[(size_t)b * NB + t];
        sc[t] = mine;
    }
    __syncthreads();
    for (int d = 1; d < NB; d <<= 1) {
        unsigned v = (t < NB && t >= d) ? sc[t - d] : 0u;
        __syncthreads();
        if (t < NB) sc[t] += v;
        __syncthreads();
    }
    if (t < NB) bStart[t] = sc[t] - mine;
    // stage points lid-order, fully coalesced (7 float4 per thread)
    if (cnt == PPB) {
        const float4* src = (const float4*)(pts + (size_t)base * 7);
        float4* dstl = (float4*)ptsS;
#pragma unroll
        for (int k = 0; k < PPB * 7 / 4 / SCT; ++k)
            dstl[k * SCT + t] = src[k * SCT + t];
    } else {
        for (int k = t; k < cnt * 7; k += SCT)
            ptsS[k] = pts[(size_t)base * 7 + k];
    }
    __syncthreads();
    // place: sorted position + packed destination (no atomics)
#pragma unroll
    for (int k = 0; k < PPB / SCT; ++k) {
        int lid = k * SCT + t;
        if (lid < cnt) {
            unsigned u = packed[base + lid];
            unsigned key = u >> 11, rank = u & 2047u;
            unsigned bk = key >> 10, sub = key & 1023u;
            unsigned sp = bStart[bk] + rank;
            sortedLid[sp] = (unsigned short)lid;
            dstp[sp] = ((runS[bk] + rank) << 10) | sub;
        }
    }
    __syncthreads();
    // emit: consecutive lanes -> consecutive slots in ~256B runs
#pragma unroll
    for (int k = 0; k < PPB / SCT; ++k) {
        int j = k * SCT + t;
        if (j < cnt) {
            int lid = sortedLid[j];
            unsigned u = dstp[j];
            unsigned d = u >> 10, sub = u & 1023u;
            const float* r = ptsS + lid * 7;
            float f0 = r[0], f1 = r[1], f2 = r[2], f3 = r[3];
            float f4 = r[4], f5 = r[5], f6 = r[6];
            float4* o = (float4*)(recs + (size_t)d * 8);
            o[0] = make_float4(f0, f1, f2, f3);
            o[1] = make_float4(f4, f5, f6, __uint_as_float(sub));
        }
    }
}

// P4: per-bucket accumulation, counting-sort into LDS, 1 atomic/record.
__global__ void __launch_bounds__(1024) rx_accum(
        const float* __restrict__ recs,
        const unsigned* __restrict__ bucketBase,
        float* __restrict__ accTable, unsigned* __restrict__ occCount) {
    __shared__ __align__(16) float sortedR[1024 * 8];   // 32 KB
    __shared__ unsigned cnt_[VPB];                      // 4 KB
    __shared__ unsigned wsum[16];
    int t = threadIdx.x, bk = blockIdx.x;
    int lane = t & 63, wid = t >> 6;
    unsigned s = bucketBase[bk], e = bucketBase[bk + 1];
    float a0 = 0.f, a1 = 0.f, a2 = 0.f, a3 = 0.f,
          a4 = 0.f, a5 = 0.f, a6 = 0.f, cf = 0.f;
    for (unsigned cs = s; cs < e; cs += 1024) {
        bool valid = (cs + t) < e;
        float4 r0, r1;
        unsigned key = 0, rank = 0;
        if (valid) {
            const float4* r = (const float4*)(recs + (size_t)(cs + t) * 8);
            r0 = r[0];
            r1 = r[1];
            key = __float_as_uint(r1.w);
        }
        cnt_[t] = 0;
        __syncthreads();
        if (valid) rank = atomicAdd(&cnt_[key], 1u);
        __syncthreads();
        unsigned own = cnt_[t];
        // hierarchical inclusive scan of own
        unsigned x = own;
#pragma unroll
        for (int d = 1; d < 64; d <<= 1) {
            unsigned y = __shfl_up(x, d, 64);
            if (lane >= d) x += y;
        }
        if (lane == 63) wsum[wid] = x;
        __syncthreads();
        if (t < 64) {
            unsigned w = (lane < 16) ? wsum[lane] : 0u;
            unsigned xx = w;
#pragma unroll
            for (int d = 1; d < 16; d <<= 1) {
                unsigned y = __shfl_up(xx, d, 64);
                if (lane >= d) xx += y;
            }
            if (lane < 16) wsum[lane] = xx - w;   // exclusive wave prefix
        }
        __syncthreads();
        unsigned excl = x - own + wsum[wid];
        cnt_[t] = excl;                           // now static offsets
        __syncthreads();
        if (valid) {
            unsigned pos = cnt_[key] + rank;
            float4* d = (float4*)&sortedR[pos * 8];
            d[0] = r0;
            d[1] = r1;
        }
        __syncthreads();
        unsigned st = excl, end = excl + own;     // thread t owns voxel t
        for (unsigned k = st; k < end; ++k) {
            float4 lo = *(const float4*)&sortedR[k * 8];
            float4 hi = *(const float4*)&sortedR[k * 8 + 4];
            a0 += lo.x; a1 += lo.y; a2 += lo.z; a3 += lo.w;
            a4 += hi.x; a5 += hi.y; a6 += hi.z; cf += 1.f;
        }
        __syncthreads();   // before cnt_/sortedR reuse next chunk
    }
    float4* o = (float4*)(accTable + ((size_t)bk * VPB + t) * 8);
    o[0] = make_float4(a0, a1, a2, a3);
    o[1] = make_float4(a4, a5, a6, cf);
    unsigned long long m = __ballot(cf > 0.f);
    if (lane == 0) wsum[wid] = (unsigned)__popcll(m);
    __syncthreads();
    if (t == 0) {
        unsigned occ = 0;
#pragma unroll
        for (int w = 0; w < 16; ++w) occ += wsum[w];
        occCount[bk] = occ;
    }
}

// P6: emit compacted means + coords from accTable
__global__ void rx_emit(const float* __restrict__ accTable,
                        const unsigned* __restrict__ rankBase,
                        float* __restrict__ out_mean,
                        float* __restrict__ out_coords) {
    int bk = blockIdx.x, t = threadIdx.x;
    float row[4][8];
    int pre[4], mycount = 0;
#pragma unroll
    for (int j = 0; j < 4; ++j) {
        int v = t * 4 + j;
        const float4* a = (const float4*)(accTable + ((size_t)bk * VPB + v) * 8);
        float4 r0 = a[0], r1 = a[1];
        row[j][0] = r0.x; row[j][1] = r0.y; row[j][2] = r0.z; row[j][3] = r0.w;
        row[j][4] = r1.x; row[j][5] = r1.y; row[j][6] = r1.z; row[j][7] = r1.w;
        pre[j] = mycount;
        mycount += (row[j][7] > 0.f) ? 1 : 0;
    }
    __shared__ int sm[256];
    sm[t] = mycount;
    __syncthreads();
    for (int off = 1; off < 256; off <<= 1) {
        int v = (t >= off) ? sm[t - off] : 0;
        __syncthreads();
        sm[t] += v;
        __syncthreads();
    }
    int rank0 = (int)rankBase[bk] + (sm[t] - mycount);
#pragma unroll
    for (int j = 0; j < 4; ++j) {
        if (row[j][7] > 0.f) {
            int r = rank0 + pre[j];
            int lin = (bk << 10) | (t * 4 + j);
            float inv = 1.0f / row[j][7];
            float* m = out_mean + (size_t)r * 7;
#pragma unroll
            for (int k = 0; k < 7; ++k) m[k] = row[j][k] * inv;
            float* cd = out_coords + (size_t)r * 3;
            cd[0] = (float)(lin >> 12);
            cd[1] = (float)((lin >> 6) & 63);
            cd[2] = (float)(lin & 63);
        }
    }
}

// ======================= FALLBACK PATH (round-3, proven) ====================
struct Meta {
    unsigned blockSums[NBLK];
    unsigned blockFlagSums[NBLK];
    unsigned blockOffs[NBLK];
    unsigned blockRankOffs[NBLK];
    unsigned nUnique;
};

__global__ void dv_count(const int* __restrict__ gi, int n,
                         unsigned* __restrict__ counts,
                         unsigned short* __restrict__ slots) {
    int i = blockIdx.x * blockDim.x + threadIdx.x;
    if (i >= n) return;
    int lin = (gi[3 * i] << 12) | (gi[3 * i + 1] << 6) | gi[3 * i + 2];
    unsigned s = atomicAdd(&counts[lin], 1u);
    slots[i] = (unsigned short)s;
}

__global__ void dv_bs1(const unsigned* __restrict__ counts,
                       Meta* __restrict__ meta) {
    int b = blockIdx.x, t = threadIdx.x;
    uint4 c = ((const uint4*)(counts + (size_t)b * 1024))[t];
    unsigned cs = c.x + c.y + c.z + c.w;
    unsigned fs = (c.x > 0) + (c.y > 0) + (c.z > 0) + (c.w > 0);
    __shared__ unsigned smC[256], smF[256];
    smC[t] = cs; smF[t] = fs;
    __syncthreads();
    for (int off = 128; off > 0; off >>= 1) {
        if (t < off) { smC[t] += smC[t + off]; smF[t] += smF[t + off]; }
        __syncthreads();
    }
    if (t == 0) { meta->blockSums[b] = smC[0]; meta->blockFlagSums[b] = smF[0]; }
}

__global__ void dv_scan2(unsigned* __restrict__ offsets, int n,
                         Meta* __restrict__ meta) {
    __shared__ unsigned smC[NBLK], smF[NBLK];
    int t = threadIdx.x;
    unsigned c = meta->blockSums[t], f = meta->blockFlagSums[t];
    smC[t] = c; smF[t] = f;
    __syncthreads();
    for (int off = 1; off < NBLK; off <<= 1) {
        unsigned vc = (t >= off) ? smC[t - off] : 0u;
        unsigned vf = (t >= off) ? smF[t - off] : 0u;
        __syncthreads();
        smC[t] += vc; smF[t] += vf;
        __syncthreads();
    }
    meta->blockOffs[t] = smC[t] - c;
    meta->blockRankOffs[t] = smF[t] - f;
    if (t == NBLK - 1) { meta->nUnique = smF[t]; offsets[NVOX] = (unsigned)n; }
}

__global__ void dv_scan3(unsigned* __restrict__ counts,
                         const Meta* __restrict__ meta) {
    int b = blockIdx.x, t = threadIdx.x;
    uint4 c = ((const uint4*)(counts + (size_t)b * 1024))[t];
    unsigned mysum = c.x + c.y + c.z + c.w;
    __shared__ unsigned sm[256];
    sm[t] = mysum;
    __syncthreads();
    for (int off = 1; off < 256; off <<= 1) {
        unsigned v = (t >= off) ? sm[t - off] : 0u;
        __syncthreads();
        sm[t] += v;
        __syncthreads();
    }
    unsigned base = meta->blockOffs[b] + sm[t] - mysum;
    uint4 o;
    o.x = base;
    o.y = base + c.x;
    o.z = o.y + c.y;
    o.w = o.z + c.z;
    ((uint4*)(counts + (size_t)b * 1024))[t] = o;
}

__global__ void dv_scatter2(const int* __restrict__ gi, int n,
                            const unsigned* __restrict__ offsets,
                            const unsigned short* __restrict__ slots,
                            unsigned* __restrict__ perm) {
    int i = blockIdx.x * blockDim.x + threadIdx.x;
    if (i >= n) return;
    int lin = (gi[3 * i] << 12) | (gi[3 * i + 1] << 6) | gi[3 * i + 2];
    perm[offsets[lin] + (unsigned)slots[i]] = (unsigned)i;
}

__global__ void dv_emit2(const float* __restrict__ points,
                         const unsigned* __restrict__ offsets,
                         const unsigned* __restrict__ perm,
                         const Meta* __restrict__ meta,
                         float* __restrict__ out_mean,
                         float* __restrict__ out_coords) {
    int b = blockIdx.x, t = threadIdx.x;
    int base = b * 1024 + t * 4;
    uint4 o4 = ((const uint4*)offsets)[b * 256 + t];
    unsigned o[5];
    o[0] = o4.x; o[1] = o4.y; o[2] = o4.z; o[3] = o4.w;
    o[4] = offsets[base + 4];
    int c[4], pre[4], mycount = 0;
#pragma unroll
    for (int j = 0; j < 4; ++j) {
        c[j] = (int)(o[j + 1] - o[j]);
        pre[j] = mycount;
        mycount += (c[j] > 0) ? 1 : 0;
    }
    __shared__ int sm[256];
    sm[t] = mycount;
    __syncthreads();
    for (int off = 1; off < 256; off <<= 1) {
        int v = (t >= off) ? sm[t - off] : 0;
        __syncthreads();
        sm[t] += v;
        __syncthreads();
    }
    int rank0 = (int)meta->blockRankOffs[b] + (sm[t] - mycount);
#pragma unroll
    for (int j = 0; j < 4; ++j) {
        if (c[j] > 0) {
            float s0 = 0.f, s1 = 0.f, s2 = 0.f, s3 = 0.f,
                  s4 = 0.f, s5 = 0.f, s6 = 0.f;
            for (unsigned k = o[j]; k < o[j + 1]; ++k) {
                unsigned idx = perm[k];
                const float* p = points + (size_t)idx * 7;
                s0 += p[0]; s1 += p[1]; s2 += p[2]; s3 += p[3];
                s4 += p[4]; s5 += p[5]; s6 += p[6];
            }
            int r = rank0 + pre[j];
            int v = base + j;
            float inv = 1.0f / (float)c[j];
            float* m = out_mean + (size_t)r * 7;
            m[0] = s0 * inv; m[1] = s1 * inv; m[2] = s2 * inv;
            m[3] = s3 * inv; m[4] = s4 * inv; m[5] = s5 * inv;
            m[6] = s6 * inv;
            float* cd = out_coords + (size_t)r * 3;
            cd[0] = (float)(v >> 12);
            cd[1] = (float)((v >> 6) & 63);
            cd[2] = (float)(v & 63);
        }
    }
}

// ======================= launch =============================================
extern "C" void kernel_launch(void* const* d_in, const int* in_sizes, int n_in,
                              void* d_out, int out_size, void* d_ws, size_t ws_size,
                              hipStream_t stream) {
    const float* points = (const float*)d_in[0];
    const int*   gi     = (const int*)d_in[1];
    int n = in_sizes[0] / 7;   // 4,000,000

    float* out_mean   = (float*)d_out;
    float* out_coords = (float*)d_out + (size_t)n * 7;

    int threads = 256;
    int nb1 = (n + PPB - 1) / PPB;

    size_t recsB = (size_t)n * 8 * sizeof(float);            // 128 MiB
    size_t pkB   = (size_t)n * sizeof(unsigned);             // 16 MiB
    size_t bhB   = (size_t)nb1 * NB * sizeof(unsigned);      // ~2 MB
    size_t accB  = (size_t)NB * VPB * 8 * sizeof(float);     // 8 MiB
    size_t need  = recsB + pkB + 2 * bhB + (NB + 1) * 4 + accB +
                   NB * 4 + NB * 4 + (NB + 1) * 4 + 256;

    size_t fillChunks = (size_t)n * 7 / 4 + (size_t)n * 3 / 4;
    int fillBlocks = (int)((fillChunks + threads - 1) / threads);

    if (ws_size >= need) {
        char* w = (char*)d_ws;
        float*    recs        = (float*)w;                 w += recsB;
        unsigned* packed      = (unsigned*)w;              w += pkB;
        unsigned* blockHist   = (unsigned*)w;              w += bhB;
        unsigned* blockOff    = (unsigned*)w;              w += bhB;
        unsigned* bucketCount = (unsigned*)w;              w += NB * 4;
        unsigned* bucketBase  = (unsigned*)w;              w += (NB + 1) * 4;
        unsigned* occCount    = (unsigned*)w;              w += NB * 4;
        unsigned* rankBase    = (unsigned*)w;              w += (NB + 1) * 4;
        float*    accTable    = (float*)w;

        rx_hist<<<nb1, SCT, 0, stream>>>(gi, n, blockHist, packed);
        rx_bucketsum<<<NB, 256, 0, stream>>>(blockHist, nb1, bucketCount);
        rx_scan256<<<1, NB, 0, stream>>>(bucketCount, bucketBase);
        rx_blockscan<<<NB, 256, 0, stream>>>(blockHist, nb1, bucketBase,
                                             blockOff);
        rx_scatter<<<nb1, SCT, 0, stream>>>(packed, points, n, blockHist,
                                            blockOff, recs);
        rx_accum<<<NB, 1024, 0, stream>>>(recs, bucketBase, accTable, occCount);
        rx_scan256<<<1, NB, 0, stream>>>(occCount, rankBase);
        rx_emit<<<NB, 256, 0, stream>>>(accTable, rankBase, out_mean, out_coords);
        dv_fill<<<fillBlocks, threads, 0, stream>>>(rankBase + NB,
                                                    (float*)d_out, n);
    } else {
        char* w = (char*)d_ws;
        unsigned*       perm    = (unsigned*)w;
        unsigned short* slots   = (unsigned short*)(w + (size_t)n * 4);
        unsigned*       offsets = (unsigned*)(w + (size_t)n * 4 + (size_t)n * 2);
        Meta*           meta    = (Meta*)((char*)offsets + (size_t)(NVOX + 4) * 4);

        hipMemsetAsync(offsets, 0, (size_t)(NVOX + 4) * 4, stream);

        int blocksN = (n + threads - 1) / threads;
        dv_count<<<blocksN, threads, 0, stream>>>(gi, n, offsets, slots);
        dv_bs1<<<NBLK, 256, 0, stream>>>(offsets, meta);
        dv_scan2<<<1, NBLK, 0, stream>>>(offsets, n, meta);
        dv_scan3<<<NBLK, 256, 0, stream>>>(offsets, meta);
        dv_scatter2<<<blocksN, threads, 0, stream>>>(gi, n, offsets, slots, perm);
        dv_emit2<<<NBLK, 256, 0, stream>>>(points, offsets, perm, meta,
                                           out_mean, out_coords);
        dv_fill<<<fillBlocks, threads, 0, stream>>>(&meta->nUnique,
                                                    (float*)d_out, n);
    }
}

// Round 10
// 386.851 us; speedup vs baseline: 1.2010x; 1.1064x over previous
//
#include <hip/hip_runtime.h>

#define NVOX 262144     // 64^3
#define NB   256        // buckets = top 8 bits of lin
#define VPB  1024       // voxels per bucket = low 10 bits
#define PPB  2048       // points per block in the fused scatter
#define SCT  512        // scatter threads
#define NBLK 256        // fallback voxel-walker blocks

// ======================= shared: padding fill ===============================
__global__ void dv_fill(const unsigned* __restrict__ nuP,
                        float* __restrict__ out, int n) {
    int nu = (int)*nuP;
    size_t meanChunks = (size_t)n * 7 / 4;
    size_t coordChunks = (size_t)n * 3 / 4;
    size_t total = meanChunks + coordChunks;
    size_t i = (size_t)blockIdx.x * blockDim.x + threadIdx.x;
    if (i >= total) return;
    float* mean = out;
    float* coords = out + (size_t)n * 7;
    if (i < meanChunks) {
        size_t base = i * 4, lim = (size_t)nu * 7;
        if (base >= lim) {
            *(float4*)(mean + base) = make_float4(0.f, 0.f, 0.f, 0.f);
        } else if (base + 4 > lim) {
            for (size_t k = lim; k < base + 4; ++k) mean[k] = 0.f;
        }
    } else {
        size_t base = (i - meanChunks) * 4, lim = (size_t)nu * 3;
        if (base >= lim) {
            *(float4*)(coords + base) = make_float4(-1.f, -1.f, -1.f, -1.f);
        } else if (base + 4 > lim) {
            for (size_t k = lim; k < base + 4; ++k) coords[k] = -1.f;
        }
    }
}

__device__ __forceinline__ unsigned bf16rne(float x) {
    unsigned u = __float_as_uint(x);
    u += 0x7fffu + ((u >> 16) & 1u);
    return u >> 16;
}

// ======================= RADIX (compressed-record) PATH =====================
// P1 (fused): per-block hist+rank (LDS atomic), global run reservation
// (1 atomic per (block,bucket)), LDS counting-sort, coalesced 16B-record emit.
// Record = uint4{b0|b1<<16, b2|b3<<16, b4|b5<<16, b6|sub<<16} (bf16 payload).
__global__ void __launch_bounds__(SCT) rx_scatfuse(
        const int* __restrict__ gi, const float* __restrict__ pts, int n,
        unsigned* __restrict__ cursor, int capb, uint4* __restrict__ recs) {
    __shared__ uint4 recS[PPB];        // 32 KB sorted records
    __shared__ unsigned dstS[PPB];     // 8 KB global record index
    __shared__ unsigned hist[NB];
    __shared__ unsigned bStart[NB];
    __shared__ unsigned runS[NB];
    int t = threadIdx.x, b = blockIdx.x;
    int base = b * PPB;
    int cnt = n - base;
    if (cnt > PPB) cnt = PPB;
    if (t < NB) hist[t] = 0;
    __syncthreads();

    // phase A: keys + ranks (1 LDS atomic per point)
    unsigned keyA[PPB / SCT], rankA[PPB / SCT];
    int p0 = base + t * 4;
    if (p0 + 4 <= n) {
        const int4* g4 = (const int4*)(gi + (size_t)base * 3);
        int4 a = g4[3 * t], c = g4[3 * t + 1], d = g4[3 * t + 2];
        keyA[0] = ((unsigned)((a.x << 2) | (a.y >> 4)) << 10) |
                  (unsigned)(((a.y & 15) << 6) | a.z);
        keyA[1] = ((unsigned)((a.w << 2) | (c.x >> 4)) << 10) |
                  (unsigned)(((c.x & 15) << 6) | c.y);
        keyA[2] = ((unsigned)((c.z << 2) | (c.w >> 4)) << 10) |
                  (unsigned)(((c.w & 15) << 6) | d.x);
        keyA[3] = ((unsigned)((d.y << 2) | (d.z >> 4)) << 10) |
                  (unsigned)(((d.z & 15) << 6) | d.w);
#pragma unroll
        for (int j = 0; j < 4; ++j)
            rankA[j] = atomicAdd(&hist[keyA[j] >> 10], 1u);
    } else {
#pragma unroll
        for (int j = 0; j < 4; ++j) {
            int i = p0 + j;
            if (i < n) {
                int g0 = gi[3 * i], g1 = gi[3 * i + 1], g2 = gi[3 * i + 2];
                keyA[j] = ((unsigned)((g0 << 2) | (g1 >> 4)) << 10) |
                          (unsigned)(((g1 & 15) << 6) | g2);
                rankA[j] = atomicAdd(&hist[keyA[j] >> 10], 1u);
            }
        }
    }
    __syncthreads();
    // exclusive scan of hist + global run reservation (order-free)
    unsigned mine = (t < NB) ? hist[t] : 0u;
    for (int d = 1; d < NB; d <<= 1) {
        unsigned v = (t < NB && t >= d) ? hist[t - d] : 0u;
        __syncthreads();
        if (t < NB) hist[t] += v;
        __syncthreads();
    }
    if (t < NB) {
        bStart[t] = hist[t] - mine;
        runS[t] = (mine > 0) ? atomicAdd(&cursor[t], mine) : 0u;
    }
    __syncthreads();

    // phase B: read point rows (dense), compress, place into sorted LDS slot
#pragma unroll
    for (int j = 0; j < PPB / SCT; ++j) {
        int lid = t * 4 + j;          // matches phase A's per-thread points
        if (lid < cnt) {
            int i = base + lid;
            const float* p = pts + (size_t)i * 7;
            float f0 = p[0], f1 = p[1], f2 = p[2], f3 = p[3];
            float f4 = p[4], f5 = p[5], f6 = p[6];
            unsigned key = keyA[j], rank = rankA[j];
            unsigned bk = key >> 10, sub = key & 1023u;
            uint4 r;
            r.x = bf16rne(f0) | (bf16rne(f1) << 16);
            r.y = bf16rne(f2) | (bf16rne(f3) << 16);
            r.z = bf16rne(f4) | (bf16rne(f5) << 16);
            r.w = bf16rne(f6) | (sub << 16);
            unsigned sp = bStart[bk] + rank;
            recS[sp] = r;
            dstS[sp] = (unsigned)bk * (unsigned)capb + runS[bk] + rank;
        }
    }
    __syncthreads();
    // phase C: coalesced emit — consecutive lanes -> consecutive slots in runs
#pragma unroll
    for (int k = 0; k < PPB / SCT; ++k) {
        int j = k * SCT + t;
        if (j < cnt) recs[dstS[j]] = recS[j];
    }
}

// P2b / P5: exclusive scan of 256 values; out[256] = total
__global__ void rx_scan256(const unsigned* __restrict__ in,
                           unsigned* __restrict__ out) {
    __shared__ unsigned sm[NB];
    int t = threadIdx.x;
    unsigned mine = in[t];
    sm[t] = mine;
    __syncthreads();
    for (int off = 1; off < NB; off <<= 1) {
        unsigned v = (t >= off) ? sm[t - off] : 0u;
        __syncthreads();
        sm[t] += v;
        __syncthreads();
    }
    out[t] = sm[t] - mine;
    if (t == NB - 1) out[NB] = sm[t];
}

// P4: per-bucket accumulation, counting-sort 2048-record chunks into LDS.
__global__ void __launch_bounds__(1024) rx_accum(
        const uint4* __restrict__ recs, const unsigned* __restrict__ cursor,
        int capb, float* __restrict__ accTable,
        unsigned* __restrict__ occCount) {
    __shared__ uint4 sortedR[2048];     // 32 KB
    __shared__ unsigned cnt_[VPB];      // 4 KB
    __shared__ unsigned wsum[16];
    int t = threadIdx.x, bk = blockIdx.x;
    int lane = t & 63, wid = t >> 6;
    unsigned len = cursor[bk];
    size_t base = (size_t)bk * (unsigned)capb;
    float a0 = 0.f, a1 = 0.f, a2 = 0.f, a3 = 0.f,
          a4 = 0.f, a5 = 0.f, a6 = 0.f, cf = 0.f;
    for (unsigned cs = 0; cs < len; cs += 2048) {
        bool v0 = (cs + t) < len, v1 = (cs + 1024 + t) < len;
        uint4 r0, r1;
        unsigned k0 = 0, k1 = 0, rk0 = 0, rk1 = 0;
        if (v0) { r0 = recs[base + cs + t]; k0 = r0.w >> 16; }
        if (v1) { r1 = recs[base + cs + 1024 + t]; k1 = r1.w >> 16; }
        cnt_[t] = 0;
        __syncthreads();
        if (v0) rk0 = atomicAdd(&cnt_[k0], 1u);
        if (v1) rk1 = atomicAdd(&cnt_[k1], 1u);
        __syncthreads();
        unsigned own = cnt_[t];
        unsigned x = own;
#pragma unroll
        for (int d = 1; d < 64; d <<= 1) {
            unsigned y = __shfl_up(x, d, 64);
            if (lane >= d) x += y;
        }
        if (lane == 63) wsum[wid] = x;
        __syncthreads();
        if (t < 64) {
            unsigned w = (lane < 16) ? wsum[lane] : 0u;
            unsigned xx = w;
#pragma unroll
            for (int d = 1; d < 16; d <<= 1) {
                unsigned y = __shfl_up(xx, d, 64);
                if (lane >= d) xx += y;
            }
            if (lane < 16) wsum[lane] = xx - w;
        }
        __syncthreads();
        unsigned excl = x - own + wsum[wid];
        cnt_[t] = excl;                 // static exclusive starts
        __syncthreads();
        if (v0) sortedR[cnt_[k0] + rk0] = r0;
        if (v1) sortedR[cnt_[k1] + rk1] = r1;
        __syncthreads();
        unsigned st = excl, end = excl + own;   // thread t owns voxel t
        for (unsigned k = st; k < end; ++k) {
            uint4 r = sortedR[k];
            a0 += __uint_as_float(r.x << 16);
            a1 += __uint_as_float(r.x & 0xffff0000u);
            a2 += __uint_as_float(r.y << 16);
            a3 += __uint_as_float(r.y & 0xffff0000u);
            a4 += __uint_as_float(r.z << 16);
            a5 += __uint_as_float(r.z & 0xffff0000u);
            a6 += __uint_as_float(r.w << 16);
            cf += 1.f;
        }
        __syncthreads();
    }
    float4* o = (float4*)(accTable + ((size_t)bk * VPB + t) * 8);
    o[0] = make_float4(a0, a1, a2, a3);
    o[1] = make_float4(a4, a5, a6, cf);
    unsigned long long m = __ballot(cf > 0.f);
    if (lane == 0) wsum[wid] = (unsigned)__popcll(m);
    __syncthreads();
    if (t == 0) {
        unsigned occ = 0;
#pragma unroll
        for (int w = 0; w < 16; ++w) occ += wsum[w];
        occCount[bk] = occ;
    }
}

// P6: emit compacted means + coords from accTable
__global__ void rx_emit(const float* __restrict__ accTable,
                        const unsigned* __restrict__ rankBase,
                        float* __restrict__ out_mean,
                        float* __restrict__ out_coords) {
    int bk = blockIdx.x, t = threadIdx.x;
    float row[4][8];
    int pre[4], mycount = 0;
#pragma unroll
    for (int j = 0; j < 4; ++j) {
        int v = t * 4 + j;
        const float4* a = (const float4*)(accTable + ((size_t)bk * VPB + v) * 8);
        float4 r0 = a[0], r1 = a[1];
        row[j][0] = r0.x; row[j][1] = r0.y; row[j][2] = r0.z; row[j][3] = r0.w;
        row[j][4] = r1.x; row[j][5] = r1.y; row[j][6] = r1.z; row[j][7] = r1.w;
        pre[j] = mycount;
        mycount += (row[j][7] > 0.f) ? 1 : 0;
    }
    __shared__ int sm[256];
    sm[t] = mycount;
    __syncthreads();
    for (int off = 1; off < 256; off <<= 1) {
        int v = (t >= off) ? sm[t - off] : 0;
        __syncthreads();
        sm[t] += v;
        __syncthreads();
    }
    int rank0 = (int)rankBase[bk] + (sm[t] - mycount);
#pragma unroll
    for (int j = 0; j < 4; ++j) {
        if (row[j][7] > 0.f) {
            int r = rank0 + pre[j];
            int lin = (bk << 10) | (t * 4 + j);
            float inv = 1.0f / row[j][7];
            float* m = out_mean + (size_t)r * 7;
#pragma unroll
            for (int k = 0; k < 7; ++k) m[k] = row[j][k] * inv;
            float* cd = out_coords + (size_t)r * 3;
            cd[0] = (float)(lin >> 12);
            cd[1] = (float)((lin >> 6) & 63);
            cd[2] = (float)(lin & 63);
        }
    }
}

// ======================= FALLBACK PATH (round-3, proven) ====================
struct Meta {
    unsigned blockSums[NBLK];
    unsigned blockFlagSums[NBLK];
    unsigned blockOffs[NBLK];
    unsigned blockRankOffs[NBLK];
    unsigned nUnique;
};

__global__ void dv_count(const int* __restrict__ gi, int n,
                         unsigned* __restrict__ counts,
                         unsigned short* __restrict__ slots) {
    int i = blockIdx.x * blockDim.x + threadIdx.x;
    if (i >= n) return;
    int lin = (gi[3 * i] << 12) | (gi[3 * i + 1] << 6) | gi[3 * i + 2];
    unsigned s = atomicAdd(&counts[lin], 1u);
    slots[i] = (unsigned short)s;
}

__global__ void dv_bs1(const unsigned* __restrict__ counts,
                       Meta* __restrict__ meta) {
    int b = blockIdx.x, t = threadIdx.x;
    uint4 c = ((const uint4*)(counts + (size_t)b * 1024))[t];
    unsigned cs = c.x + c.y + c.z + c.w;
    unsigned fs = (c.x > 0) + (c.y > 0) + (c.z > 0) + (c.w > 0);
    __shared__ unsigned smC[256], smF[256];
    smC[t] = cs; smF[t] = fs;
    __syncthreads();
    for (int off = 128; off > 0; off >>= 1) {
        if (t < off) { smC[t] += smC[t + off]; smF[t] += smF[t + off]; }
        __syncthreads();
    }
    if (t == 0) { meta->blockSums[b] = smC[0]; meta->blockFlagSums[b] = smF[0]; }
}

__global__ void dv_scan2(unsigned* __restrict__ offsets, int n,
                         Meta* __restrict__ meta) {
    __shared__ unsigned smC[NBLK], smF[NBLK];
    int t = threadIdx.x;
    unsigned c = meta->blockSums[t], f = meta->blockFlagSums[t];
    smC[t] = c; smF[t] = f;
    __syncthreads();
    for (int off = 1; off < NBLK; off <<= 1) {
        unsigned vc = (t >= off) ? smC[t - off] : 0u;
        unsigned vf = (t >= off) ? smF[t - off] : 0u;
        __syncthreads();
        smC[t] += vc; smF[t] += vf;
        __syncthreads();
    }
    meta->blockOffs[t] = smC[t] - c;
    meta->blockRankOffs[t] = smF[t] - f;
    if (t == NBLK - 1) { meta->nUnique = smF[t]; offsets[NVOX] = (unsigned)n; }
}

__global__ void dv_scan3(unsigned* __restrict__ counts,
                         const Meta* __restrict__ meta) {
    int b = blockIdx.x, t = threadIdx.x;
    uint4 c = ((const uint4*)(counts + (size_t)b * 1024))[t];
    unsigned mysum = c.x + c.y + c.z + c.w;
    __shared__ unsigned sm[256];
    sm[t] = mysum;
    __syncthreads();
    for (int off = 1; off < 256; off <<= 1) {
        unsigned v = (t >= off) ? sm[t - off] : 0u;
        __syncthreads();
        sm[t] += v;
        __syncthreads();
    }
    unsigned base = meta->blockOffs[b] + sm[t] - mysum;
    uint4 o;
    o.x = base;
    o.y = base + c.x;
    o.z = o.y + c.y;
    o.w = o.z + c.z;
    ((uint4*)(counts + (size_t)b * 1024))[t] = o;
}

__global__ void dv_scatter2(const int* __restrict__ gi, int n,
                            const unsigned* __restrict__ offsets,
                            const unsigned short* __restrict__ slots,
                            unsigned* __restrict__ perm) {
    int i = blockIdx.x * blockDim.x + threadIdx.x;
    if (i >= n) return;
    int lin = (gi[3 * i] << 12) | (gi[3 * i + 1] << 6) | gi[3 * i + 2];
    perm[offsets[lin] + (unsigned)slots[i]] = (unsigned)i;
}

__global__ void dv_emit2(const float* __restrict__ points,
                         const unsigned* __restrict__ offsets,
                         const unsigned* __restrict__ perm,
                         const Meta* __restrict__ meta,
                         float* __restrict__ out_mean,
                         float* __restrict__ out_coords) {
    int b = blockIdx.x, t = threadIdx.x;
    int base = b * 1024 + t * 4;
    uint4 o4 = ((const uint4*)offsets)[b * 256 + t];
    unsigned o[5];
    o[0] = o4.x; o[1] = o4.y; o[2] = o4.z; o[3] = o4.w;
    o[4] = offsets[base + 4];
    int c[4], pre[4], mycount = 0;
#pragma unroll
    for (int j = 0; j < 4; ++j) {
        c[j] = (int)(o[j + 1] - o[j]);
        pre[j] = mycount;
        mycount += (c[j] > 0) ? 1 : 0;
    }
    __shared__ int sm[256];
    sm[t] = mycount;
    __syncthreads();
    for (int off = 1; off < 256; off <<= 1) {
        int v = (t >= off) ? sm[t - off] : 0;
        __syncthreads();
        sm[t] += v;
        __syncthreads();
    }
    int rank0 = (int)meta->blockRankOffs[b] + (sm[t] - mycount);
#pragma unroll
    for (int j = 0; j < 4; ++j) {
        if (c[j] > 0) {
            float s0 = 0.f, s1 = 0.f, s2 = 0.f, s3 = 0.f,
                  s4 = 0.f, s5 = 0.f, s6 = 0.f;
            for (unsigned k = o[j]; k < o[j + 1]; ++k) {
                unsigned idx = perm[k];
                const float* p = points + (size_t)idx * 7;
                s0 += p[0]; s1 += p[1]; s2 += p[2]; s3 += p[3];
                s4 += p[4]; s5 += p[5]; s6 += p[6];
            }
            int r = rank0 + pre[j];
            int v = base + j;
            float inv = 1.0f / (float)c[j];
            float* m = out_mean + (size_t)r * 7;
            m[0] = s0 * inv; m[1] = s1 * inv; m[2] = s2 * inv;
            m[3] = s3 * inv; m[4] = s4 * inv; m[5] = s5 * inv;
            m[6] = s6 * inv;
            float* cd = out_coords + (size_t)r * 3;
            cd[0] = (float)(v >> 12);
            cd[1] = (float)((v >> 6) & 63);
            cd[2] = (float)(v & 63);
        }
    }
}

// ======================= launch =============================================
extern "C" void kernel_launch(void* const* d_in, const int* in_sizes, int n_in,
                              void* d_out, int out_size, void* d_ws, size_t ws_size,
                              hipStream_t stream) {
    const float* points = (const float*)d_in[0];
    const int*   gi     = (const int*)d_in[1];
    int n = in_sizes[0] / 7;   // 4,000,000

    float* out_mean   = (float*)d_out;
    float* out_coords = (float*)d_out + (size_t)n * 7;

    int threads = 256;
    int nb1 = (n + PPB - 1) / PPB;

    // per-bucket capacity: mean + ~13% + 1024 (>=20 sigma for binomial spread)
    int capb = n / NB + n / NB / 8 + 1024;
    size_t recsB = (size_t)NB * capb * 16;                   // ~76 MB
    size_t accB  = (size_t)NB * VPB * 8 * sizeof(float);     // 8 MiB
    size_t need  = recsB + accB + NB * 4 /*cursor*/ + NB * 4 /*occCount*/ +
                   (NB + 1) * 4 /*rankBase*/ + 256;

    size_t fillChunks = (size_t)n * 7 / 4 + (size_t)n * 3 / 4;
    int fillBlocks = (int)((fillChunks + threads - 1) / threads);

    if (ws_size >= need) {
        char* w = (char*)d_ws;
        uint4*    recs     = (uint4*)w;                    w += recsB;
        float*    accTable = (float*)w;                    w += accB;
        unsigned* cursor   = (unsigned*)w;                 w += NB * 4;
        unsigned* occCount = (unsigned*)w;                 w += NB * 4;
        unsigned* rankBase = (unsigned*)w;

        hipMemsetAsync(cursor, 0, NB * 4, stream);
        rx_scatfuse<<<nb1, SCT, 0, stream>>>(gi, points, n, cursor, capb, recs);
        rx_accum<<<NB, 1024, 0, stream>>>(recs, cursor, capb, accTable,
                                          occCount);
        rx_scan256<<<1, NB, 0, stream>>>(occCount, rankBase);
        rx_emit<<<NB, 256, 0, stream>>>(accTable, rankBase, out_mean,
                                        out_coords);
        dv_fill<<<fillBlocks, threads, 0, stream>>>(rankBase + NB,
                                                    (float*)d_out, n);
    } else {
        char* w = (char*)d_ws;
        unsigned*       perm    = (unsigned*)w;
        unsigned short* slots   = (unsigned short*)(w + (size_t)n * 4);
        unsigned*       offsets = (unsigned*)(w + (size_t)n * 4 + (size_t)n * 2);
        Meta*           meta    = (Meta*)((char*)offsets + (size_t)(NVOX + 4) * 4);

        hipMemsetAsync(offsets, 0, (size_t)(NVOX + 4) * 4, stream);

        int blocksN = (n + threads - 1) / threads;
        dv_count<<<blocksN, threads, 0, stream>>>(gi, n, offsets, slots);
        dv_bs1<<<NBLK, 256, 0, stream>>>(offsets, meta);
        dv_scan2<<<1, NBLK, 0, stream>>>(offsets, n, meta);
        dv_scan3<<<NBLK, 256, 0, stream>>>(offsets, meta);
        dv_scatter2<<<blocksN, threads, 0, stream>>>(gi, n, offsets, slots, perm);
        dv_emit2<<<NBLK, 256, 0, stream>>>(points, offsets, perm, meta,
                                           out_mean, out_coords);
        dv_fill<<<fillBlocks, threads, 0, stream>>>(&meta->nUnique,
                                                    (float*)d_out, n);
    }
}